// Round 10
// baseline (328.290 us; speedup 1.0000x reference)
//
#include <hip/hip_runtime.h>
#include <hip/hip_bf16.h>
#include <math.h>

// Problem constants (fixed by the reference):
// N=20000, E=320000, DIN=128, DH=64, H=8, B=16, C=10, NEG_SLOPE=0.2

#define NEG_SLOPE 0.2f

typedef float f32x2 __attribute__((ext_vector_type(2)));
typedef float f32x4 __attribute__((ext_vector_type(4)));
typedef short bf16x8 __attribute__((ext_vector_type(8)));

__device__ __forceinline__ float bf2f(__hip_bfloat16 b) { return __bfloat162float(b); }
__device__ __forceinline__ unsigned short f2bfu(float x) {
    __hip_bfloat16 b = __float2bfloat16(x);
    return *(unsigned short*)&b;
}

// fp8 e4m3 pack/unpack (OCP on gfx950)
__device__ __forceinline__ unsigned char f2fp8(float x) {
    unsigned int u = __builtin_amdgcn_cvt_pk_fp8_f32(x, x, 0, false);
    return (unsigned char)(u & 0xff);
}
__device__ __forceinline__ void unpack8_fp8(uint2 u, float* f) {
    f32x2 a = __builtin_amdgcn_cvt_pk_f32_fp8(u.x, false);
    f32x2 b = __builtin_amdgcn_cvt_pk_f32_fp8(u.x, true);
    f32x2 c = __builtin_amdgcn_cvt_pk_f32_fp8(u.y, false);
    f32x2 d = __builtin_amdgcn_cvt_pk_f32_fp8(u.y, true);
    f[0] = a[0]; f[1] = a[1]; f[2] = b[0]; f[3] = b[1];
    f[4] = c[0]; f[5] = c[1]; f[6] = d[0]; f[7] = d[1];
}

// ---------------- prep_all: W-swizzle both layers + zero cnt (replaces 2 wswiz + 2 memsets) --
// blocks 0..15: W1 swizzle; 16..31: W2 swizzle; 32..35: zero cnt.
// Frag layout: Wswz[((ctg*2+ks)*64 + lane)*8 + j] = bf16(W[ks*32 + (lane>>4)*8 + j][ctg*16 + (lane&15)])
__global__ __launch_bounds__(256) void prep_all(const float* __restrict__ W1,
                                                const float* __restrict__ W2,
                                                unsigned short* __restrict__ Bz1,
                                                unsigned short* __restrict__ Bz2,
                                                int* __restrict__ cnt, int N) {
    int b = blockIdx.x;
    if (b < 32) {
        const float* W = (b < 16) ? W1 : W2;
        unsigned short* Wswz = (b < 16) ? Bz1 : Bz2;
        int fid = (b & 15) * 256 + threadIdx.x;     // 0..4095
        int lane = fid & 63;
        int ks = (fid >> 6) & 1;
        int ctg = fid >> 7;                          // 0..31
        int col = ctg * 16 + (lane & 15);
        int k0 = ks * 32 + ((lane >> 4) << 3);
        unsigned short v[8];
#pragma unroll
        for (int j = 0; j < 8; ++j) v[j] = f2bfu(W[(k0 + j) * 512 + col]);
        ushort4* dst = (ushort4*)(Wswz + (size_t)fid * 8);
        dst[0] = make_ushort4(v[0], v[1], v[2], v[3]);
        dst[1] = make_ushort4(v[4], v[5], v[6], v[7]);
    } else {
        for (int i = (b - 32) * 256 + threadIdx.x; i < N; i += 4 * 256) cnt[i] = 0;
    }
}

// ---------------- CSR build ----------------
__global__ void hist_kernel(const int* __restrict__ dst, int* __restrict__ cnt, int E) {
    int e = blockIdx.x * 256 + threadIdx.x;
    if (e < E) atomicAdd(&cnt[dst[e]], 1);
}

__global__ __launch_bounds__(1024) void scan_kernel(const int* __restrict__ cnt,
                                                    int* __restrict__ row_start,
                                                    int* __restrict__ cursor, int N) {
    __shared__ int part[1024];
    int t = threadIdx.x;
    int CH = (N + 1023) >> 10;
    int beg = t * CH;
    int end = beg + CH; if (end > N) end = N;
    if (beg > N) beg = N;
    int local = 0;
    for (int i = beg; i < end; ++i) local += cnt[i];
    part[t] = local;
    __syncthreads();
    for (int off = 1; off < 1024; off <<= 1) {
        int v = (t >= off) ? part[t - off] : 0;
        __syncthreads();
        part[t] += v;
        __syncthreads();
    }
    int run = part[t] - local;   // exclusive prefix
    for (int i = beg; i < end; ++i) {
        row_start[i] = run; cursor[i] = run;
        run += cnt[i];
    }
    if (t == 1023) row_start[N] = run;   // == E
}

__global__ void scatter_kernel(const int* __restrict__ src, const int* __restrict__ dst,
                               int* __restrict__ cursor, int* __restrict__ src_sorted, int E) {
    int e = blockIdx.x * 256 + threadIdx.x;
    if (e < E) {
        int p = atomicAdd(&cursor[dst[e]], 1);
        src_sorted[p] = src[e];
    }
}

// ---------------- input GEMM: h0 = g_feats @ W_in + b_in   [N,128]x[128,64] ----------------
__global__ __launch_bounds__(256) void in_gemm(const float* __restrict__ g,
                                               const float* __restrict__ W,
                                               const float* __restrict__ b,
                                               float* __restrict__ h0, int N) {
    __shared__ float gt[128][36];   // gt[k][r]
    int t = threadIdx.x;
    int n0 = blockIdx.x * 32;
#pragma unroll
    for (int i = 0; i < 4; ++i) {
        int ch = t + i * 256;           // 1024 float4 chunks: 32 rows x 32 chunks
        int r = ch >> 5, k0 = (ch & 31) << 2;
        float4 v = (n0 + r < N) ? *(const float4*)(g + (size_t)(n0 + r) * 128 + k0)
                                : make_float4(0.f, 0.f, 0.f, 0.f);
        gt[k0 + 0][r] = v.x; gt[k0 + 1][r] = v.y; gt[k0 + 2][r] = v.z; gt[k0 + 3][r] = v.w;
    }
    __syncthreads();
    int c = t & 63, rg = t >> 6;
    float acc[8];
#pragma unroll
    for (int j = 0; j < 8; ++j) acc[j] = 0.f;
#pragma unroll 4
    for (int k = 0; k < 128; ++k) {
        float w = W[k * 64 + c];
        const float* hp = &gt[k][rg * 8];
        float4 ha = *(const float4*)hp;
        float4 hb = *(const float4*)(hp + 4);
        acc[0] = fmaf(ha.x, w, acc[0]);
        acc[1] = fmaf(ha.y, w, acc[1]);
        acc[2] = fmaf(ha.z, w, acc[2]);
        acc[3] = fmaf(ha.w, w, acc[3]);
        acc[4] = fmaf(hb.x, w, acc[4]);
        acc[5] = fmaf(hb.y, w, acc[5]);
        acc[6] = fmaf(hb.z, w, acc[6]);
        acc[7] = fmaf(hb.w, w, acc[7]);
    }
    float bb = b[c];
#pragma unroll
    for (int j = 0; j < 8; ++j) {
        int r = rg * 8 + j;
        if (n0 + r < N) h0[(size_t)(n0 + r) * 64 + c] = acc[j] + bb;
    }
}

// ---------------- feat GEMM (MFMA bf16) + el/er epilogue -> fp8 feat ----------------
__global__ __launch_bounds__(512) void feat_gemm(const float* __restrict__ hin,
                                                 const unsigned short* __restrict__ Wswz,
                                                 const float* __restrict__ al,
                                                 const float* __restrict__ ar,
                                                 unsigned char* __restrict__ feat8,
                                                 __hip_bfloat16* __restrict__ el,
                                                 __hip_bfloat16* __restrict__ er, int N) {
    __shared__ unsigned short shA[32][72];        // bf16, padded
    __shared__ unsigned char sfp8[32][512];       // fp8 output staging
    int t = threadIdx.x;
    int n0 = blockIdx.x * 32;
    {
        int r = t >> 4, c0 = (t & 15) << 2;
        float4 v = (n0 + r < N) ? *(const float4*)(hin + (size_t)(n0 + r) * 64 + c0)
                                : make_float4(0.f, 0.f, 0.f, 0.f);
        *(ushort4*)&shA[r][c0] = make_ushort4(f2bfu(v.x), f2bfu(v.y), f2bfu(v.z), f2bfu(v.w));
    }
    __syncthreads();

    int lane = t & 63;
    int w = t >> 6;              // wave id == head
    int lr = lane & 15;
    int lg = lane >> 4;          // 0..3

    bf16x8 afrag[2][2];
#pragma unroll
    for (int rt = 0; rt < 2; ++rt)
#pragma unroll
        for (int ks = 0; ks < 2; ++ks)
            afrag[rt][ks] = *(const bf16x8*)&shA[rt * 16 + lr][ks * 32 + lg * 8];

    bf16x8 bfrag[4][2];
#pragma unroll
    for (int ct = 0; ct < 4; ++ct)
#pragma unroll
        for (int ks = 0; ks < 2; ++ks) {
            int fid = ((w * 4 + ct) * 2 + ks) * 64 + lane;
            bfrag[ct][ks] = *(const bf16x8*)(Wswz + (size_t)fid * 8);
        }

    f32x4 acc[2][4];
#pragma unroll
    for (int rt = 0; rt < 2; ++rt)
#pragma unroll
        for (int ct = 0; ct < 4; ++ct)
            acc[rt][ct] = (f32x4){0.f, 0.f, 0.f, 0.f};

#pragma unroll
    for (int rt = 0; rt < 2; ++rt)
#pragma unroll
        for (int ct = 0; ct < 4; ++ct) {
            acc[rt][ct] = __builtin_amdgcn_mfma_f32_16x16x32_bf16(afrag[rt][0], bfrag[ct][0], acc[rt][ct], 0, 0, 0);
            acc[rt][ct] = __builtin_amdgcn_mfma_f32_16x16x32_bf16(afrag[rt][1], bfrag[ct][1], acc[rt][ct], 0, 0, 0);
        }

    // ---- epilogue 1: fp8 into LDS (transpose for coalesced global store)
#pragma unroll
    for (int rt = 0; rt < 2; ++rt)
#pragma unroll
        for (int ct = 0; ct < 4; ++ct) {
            int col = w * 64 + ct * 16 + lr;
#pragma unroll
            for (int j = 0; j < 4; ++j)
                sfp8[rt * 16 + lg * 4 + j][col] = f2fp8(acc[rt][ct][j]);
        }

    // ---- epilogue 2: el/er partials (register-only)
    float alv[4], arv[4];
#pragma unroll
    for (int ct = 0; ct < 4; ++ct) {
        alv[ct] = al[w * 64 + ct * 16 + lr];
        arv[ct] = ar[w * 64 + ct * 16 + lr];
    }
    float elp[2][4], erp[2][4];
#pragma unroll
    for (int rt = 0; rt < 2; ++rt)
#pragma unroll
        for (int j = 0; j < 4; ++j) {
            float sl = 0.f, sr = 0.f;
#pragma unroll
            for (int ct = 0; ct < 4; ++ct) {
                sl = fmaf(acc[rt][ct][j], alv[ct], sl);
                sr = fmaf(acc[rt][ct][j], arv[ct], sr);
            }
            elp[rt][j] = sl; erp[rt][j] = sr;
        }
#pragma unroll
    for (int off = 1; off < 16; off <<= 1)
#pragma unroll
        for (int rt = 0; rt < 2; ++rt)
#pragma unroll
            for (int j = 0; j < 4; ++j) {
                elp[rt][j] += __shfl_xor(elp[rt][j], off, 64);
                erp[rt][j] += __shfl_xor(erp[rt][j], off, 64);
            }
    if (lr == 0) {
#pragma unroll
        for (int rt = 0; rt < 2; ++rt)
#pragma unroll
            for (int j = 0; j < 4; ++j) {
                int r = rt * 16 + lg * 4 + j;
                if (n0 + r < N) {
                    el[(size_t)(n0 + r) * 8 + w] = __float2bfloat16(elp[rt][j]);
                    er[(size_t)(n0 + r) * 8 + w] = __float2bfloat16(erp[rt][j]);
                }
            }
    }

    // ---- coalesced fp8 store
    __syncthreads();
    {
        const uint4* src = (const uint4*)&sfp8[0][0];
        uint4* dst = (uint4*)(feat8 + (size_t)n0 * 512);
        int i0 = t * 2;
        if ((size_t)n0 * 512 + (size_t)(i0 + 2) * 16 <= (size_t)N * 512) {
            dst[i0] = src[i0];
            dst[i0 + 1] = src[i0 + 1];
        }
    }
}

// ---------------- GAT aggregation: one wave per dst node, single pass, fp8 feat ----------
// Per 8-edge sub-chunk, lane (h*8+e) computes THE exp for (edge e, head h);
// gather loop shfl-broadcasts alpha & src, 8 independent 8B loads in flight.
// __launch_bounds__(256, 8) pins regalloc under the 64-VGPR occupancy step (R6 lesson).
template <bool RELU>
__global__ __launch_bounds__(256, 8) void gat_aggregate(
    const unsigned char* __restrict__ feat8, const __hip_bfloat16* __restrict__ el,
    const __hip_bfloat16* __restrict__ er, const float* __restrict__ bias,
    const int* __restrict__ row_start, const int* __restrict__ src_sorted,
    float* __restrict__ hout, int N) {
    int lane = threadIdx.x & 63;
    int n = blockIdx.x * 4 + (threadIdx.x >> 6);
    if (n >= N) return;
    int h = lane >> 3;
    float erh = bf2f(er[(size_t)n * 8 + h]);
    int row = row_start[n];
    int deg = row_start[n + 1] - row;
    const unsigned char* featl = feat8 + lane * 8;  // per-lane base

    float acc[8];
#pragma unroll
    for (int j = 0; j < 8; ++j) acc[j] = 0.f;
    float den = 0.f;

    for (int base = 0; base < deg; base += 64) {
        int cnt = min(deg - base, 64);
        int sv = (lane < cnt) ? src_sorted[row + base + lane] : 0;
        int nsub = cnt & ~7;
        for (int i0 = 0; i0 < nsub; i0 += 8) {
            // exp-dedup: this lane owns (edge = i0 + (lane&7), head = lane>>3)
            int se = __shfl(sv, i0 + (lane & 7), 64);
            float ve = bf2f(el[(size_t)se * 8 + h]) + erh;
            ve = fmaxf(ve, NEG_SLOPE * ve);
            float am = __expf(ve);
            int hb = lane & 0x38;
#pragma unroll
            for (int e = 0; e < 8; ++e) {
                float a = __shfl(am, hb | e, 64);
                int s = __shfl(sv, i0 + e, 64);
                uint2 u = *(const uint2*)(featl + (size_t)s * 512);
                den += a;
                float f[8];
                unpack8_fp8(u, f);
#pragma unroll
                for (int j = 0; j < 8; ++j) acc[j] = fmaf(a, f[j], acc[j]);
            }
        }
        for (int i = nsub; i < cnt; ++i) {
            int s = __shfl(sv, i, 64);
            uint2 u = *(const uint2*)(featl + (size_t)s * 512);
            float v = bf2f(el[(size_t)s * 8 + h]) + erh;
            v = fmaxf(v, NEG_SLOPE * v);
            float a = __expf(v);
            den += a;
            float f[8];
            unpack8_fp8(u, f);
#pragma unroll
            for (int j = 0; j < 8; ++j) acc[j] = fmaf(a, f[j], acc[j]);
        }
    }

    float invd = deg > 0 ? 1.f / den : 0.f;
    const float4* bp = (const float4*)(bias + lane * 8);
    float4 b0 = bp[0], b1 = bp[1];
    float o[8];
    o[0] = fmaf(acc[0], invd, b0.x); o[1] = fmaf(acc[1], invd, b0.y);
    o[2] = fmaf(acc[2], invd, b0.z); o[3] = fmaf(acc[3], invd, b0.w);
    o[4] = fmaf(acc[4], invd, b1.x); o[5] = fmaf(acc[5], invd, b1.y);
    o[6] = fmaf(acc[6], invd, b1.z); o[7] = fmaf(acc[7], invd, b1.w);

    // head-mean: sum across lanes differing in head bits (3,4,5)
#pragma unroll
    for (int off = 8; off < 64; off <<= 1)
#pragma unroll
        for (int j = 0; j < 8; ++j)
            o[j] += __shfl_xor(o[j], off, 64);

    if (lane < 8) {
#pragma unroll
        for (int j = 0; j < 8; ++j) {
            o[j] *= 0.125f;
            if (RELU) o[j] = fmaxf(o[j], 0.f);
        }
        float4* op = (float4*)(hout + (size_t)n * 64 + lane * 8);
        op[0] = make_float4(o[0], o[1], o[2], o[3]);
        op[1] = make_float4(o[4], o[5], o[6], o[7]);
    }
}

// ---------------- graph_head: one block per graph (replaces readout_partial + head_kernel) --
// Node range via binary search on sorted gids; sum rows, mean, 64x10 GEMM, softmax.
__global__ __launch_bounds__(256) void graph_head(const float* __restrict__ h2,
                                                  const int* __restrict__ gid,
                                                  const float* __restrict__ W_head,
                                                  const float* __restrict__ b_head,
                                                  float* __restrict__ out, int N) {
    __shared__ float part[4][64];
    __shared__ float smean[64];
    __shared__ float slog[10];
    int g = blockIdx.x;
    int t = threadIdx.x;
    int lo = 0, hi = N;
    while (lo < hi) { int m = (lo + hi) >> 1; if (gid[m] < g) lo = m + 1; else hi = m; }
    int beg = lo;
    lo = 0; hi = N;
    while (lo < hi) { int m = (lo + hi) >> 1; if (gid[m] < g + 1) lo = m + 1; else hi = m; }
    int end = lo;

    int c = t & 63, r = t >> 6;
    float sum = 0.f;
    for (int n = beg + r; n < end; n += 4) sum += h2[(size_t)n * 64 + c];
    part[r][c] = sum;
    __syncthreads();
    if (t < 64) {
        float s = part[0][t] + part[1][t] + part[2][t] + part[3][t];
        smean[t] = s / fmaxf((float)(end - beg), 1.f);
    }
    __syncthreads();
    if (t < 10) {
        float acc = b_head[t];
#pragma unroll 16
        for (int k = 0; k < 64; ++k) acc = fmaf(smean[k], W_head[k * 10 + t], acc);
        slog[t] = acc;
    }
    __syncthreads();
    if (t == 0) {
        float mx = -INFINITY;
#pragma unroll
        for (int cc = 0; cc < 10; ++cc) mx = fmaxf(mx, slog[cc]);
        float e[10], s = 0.f;
#pragma unroll
        for (int cc = 0; cc < 10; ++cc) { e[cc] = __expf(slog[cc] - mx); s += e[cc]; }
        float inv = 1.f / s;
#pragma unroll
        for (int cc = 0; cc < 10; ++cc) out[g * 10 + cc] = e[cc] * inv;
    }
}

extern "C" void kernel_launch(void* const* d_in, const int* in_sizes, int n_in,
                              void* d_out, int out_size, void* d_ws, size_t ws_size,
                              hipStream_t stream) {
    const float* g_feats  = (const float*)d_in[0];
    const int*   edge_src = (const int*)d_in[1];
    const int*   edge_dst = (const int*)d_in[2];
    const int*   gids     = (const int*)d_in[3];
    const float* W_in     = (const float*)d_in[4];
    const float* b_in     = (const float*)d_in[5];
    const float* W1       = (const float*)d_in[6];
    const float* attn_l1  = (const float*)d_in[7];
    const float* attn_r1  = (const float*)d_in[8];
    const float* bias1    = (const float*)d_in[9];
    const float* W2       = (const float*)d_in[10];
    const float* attn_l2  = (const float*)d_in[11];
    const float* attn_r2  = (const float*)d_in[12];
    const float* bias2    = (const float*)d_in[13];
    const float* W_head   = (const float*)d_in[14];
    const float* b_head   = (const float*)d_in[15];
    float* out = (float*)d_out;

    const int N = in_sizes[3];
    const int E = in_sizes[1];

    // workspace layout (16B-aligned sections)
    unsigned char* feat8 = (unsigned char*)d_ws;            // N*512 bytes (fp8)
    float* h0 = (float*)(feat8 + (size_t)N * 512);          // N*64 f32
    float* h1 = h0 + (size_t)N * 64;                        // N*64
    float* h2 = h1 + (size_t)N * 64;                        // N*64
    __hip_bfloat16* el = (__hip_bfloat16*)(h2 + (size_t)N * 64);  // N*8 bf16
    __hip_bfloat16* er = el + (size_t)N * 8;                // N*8 bf16
    unsigned short* Wz1 = (unsigned short*)(er + (size_t)N * 8);  // 32768 bf16
    unsigned short* Wz2 = Wz1 + 32768;                      // 32768 bf16
    int* cnt        = (int*)(Wz2 + 32768);                  // N
    int* row_start  = cnt + N;                              // N+1
    int* cursor     = row_start + N + 1;                    // N
    int* src_sorted = cursor + N;                           // E

    int eb = (E + 255) / 256;
    int nb4 = (N + 3) / 4;
    int nb32 = (N + 31) / 32;

    prep_all<<<36, 256, 0, stream>>>(W1, W2, Wz1, Wz2, cnt, N);
    hist_kernel<<<eb, 256, 0, stream>>>(edge_dst, cnt, E);
    scan_kernel<<<1, 1024, 0, stream>>>(cnt, row_start, cursor, N);
    scatter_kernel<<<eb, 256, 0, stream>>>(edge_src, edge_dst, cursor, src_sorted, E);

    in_gemm<<<nb32, 256, 0, stream>>>(g_feats, W_in, b_in, h0, N);

    feat_gemm<<<nb32, 512, 0, stream>>>(h0, Wz1, attn_l1, attn_r1, feat8, el, er, N);
    gat_aggregate<true><<<nb4, 256, 0, stream>>>(feat8, el, er, bias1, row_start, src_sorted, h1, N);

    feat_gemm<<<nb32, 512, 0, stream>>>(h1, Wz2, attn_l2, attn_r2, feat8, el, er, N);
    gat_aggregate<false><<<nb4, 256, 0, stream>>>(feat8, el, er, bias2, row_start, src_sorted, h2, N);

    graph_head<<<16, 256, 0, stream>>>(h2, gids, W_head, b_head, out, N);
}

// Round 12
// 288.818 us; speedup vs baseline: 1.1367x; 1.1367x over previous
//
#include <hip/hip_runtime.h>
#include <hip/hip_bf16.h>
#include <math.h>

// Problem constants (fixed by the reference):
// N=20000, E=320000, DIN=128, DH=64, H=8, B=16, C=10, NEG_SLOPE=0.2

#define NEG_SLOPE 0.2f

typedef float f32x2 __attribute__((ext_vector_type(2)));
typedef float f32x4 __attribute__((ext_vector_type(4)));
typedef short bf16x8 __attribute__((ext_vector_type(8)));

__device__ __forceinline__ float bf2f(__hip_bfloat16 b) { return __bfloat162float(b); }
__device__ __forceinline__ unsigned short f2bfu(float x) {
    __hip_bfloat16 b = __float2bfloat16(x);
    return *(unsigned short*)&b;
}

// fp8 e4m3 pack/unpack (OCP on gfx950)
__device__ __forceinline__ unsigned char f2fp8(float x) {
    unsigned int u = __builtin_amdgcn_cvt_pk_fp8_f32(x, x, 0, false);
    return (unsigned char)(u & 0xff);
}
__device__ __forceinline__ void unpack8_fp8(uint2 u, float* f) {
    f32x2 a = __builtin_amdgcn_cvt_pk_f32_fp8(u.x, false);
    f32x2 b = __builtin_amdgcn_cvt_pk_f32_fp8(u.x, true);
    f32x2 c = __builtin_amdgcn_cvt_pk_f32_fp8(u.y, false);
    f32x2 d = __builtin_amdgcn_cvt_pk_f32_fp8(u.y, true);
    f[0] = a[0]; f[1] = a[1]; f[2] = b[0]; f[3] = b[1];
    f[4] = c[0]; f[5] = c[1]; f[6] = d[0]; f[7] = d[1];
}

// ---------------- prep_all: W-swizzle both layers + zero cnt & hg (no memsets needed) ------
// blocks 0..15: W1 swizzle; 16..31: W2 swizzle; 32..35: zero cnt; block 32 also zeroes hg.
__global__ __launch_bounds__(256) void prep_all(const float* __restrict__ W1,
                                                const float* __restrict__ W2,
                                                unsigned short* __restrict__ Bz1,
                                                unsigned short* __restrict__ Bz2,
                                                int* __restrict__ cnt,
                                                float* __restrict__ hg, int N) {
    int b = blockIdx.x;
    if (b < 32) {
        const float* W = (b < 16) ? W1 : W2;
        unsigned short* Wswz = (b < 16) ? Bz1 : Bz2;
        int fid = (b & 15) * 256 + threadIdx.x;     // 0..4095
        int lane = fid & 63;
        int ks = (fid >> 6) & 1;
        int ctg = fid >> 7;                          // 0..31
        int col = ctg * 16 + (lane & 15);
        int k0 = ks * 32 + ((lane >> 4) << 3);
        unsigned short v[8];
#pragma unroll
        for (int j = 0; j < 8; ++j) v[j] = f2bfu(W[(k0 + j) * 512 + col]);
        ushort4* dst = (ushort4*)(Wswz + (size_t)fid * 8);
        dst[0] = make_ushort4(v[0], v[1], v[2], v[3]);
        dst[1] = make_ushort4(v[4], v[5], v[6], v[7]);
    } else {
        for (int i = (b - 32) * 256 + threadIdx.x; i < N; i += 4 * 256) cnt[i] = 0;
        if (b == 32) {
            for (int i = threadIdx.x; i < 16 * 64; i += 256) hg[i] = 0.f;
        }
    }
}

// ---------------- CSR build ----------------
__global__ void hist_kernel(const int* __restrict__ dst, int* __restrict__ cnt, int E) {
    int e = blockIdx.x * 256 + threadIdx.x;
    if (e < E) atomicAdd(&cnt[dst[e]], 1);
}

__global__ __launch_bounds__(1024) void scan_kernel(const int* __restrict__ cnt,
                                                    int* __restrict__ row_start,
                                                    int* __restrict__ cursor, int N) {
    __shared__ int part[1024];
    int t = threadIdx.x;
    int CH = (N + 1023) >> 10;
    int beg = t * CH;
    int end = beg + CH; if (end > N) end = N;
    if (beg > N) beg = N;
    int local = 0;
    for (int i = beg; i < end; ++i) local += cnt[i];
    part[t] = local;
    __syncthreads();
    for (int off = 1; off < 1024; off <<= 1) {
        int v = (t >= off) ? part[t - off] : 0;
        __syncthreads();
        part[t] += v;
        __syncthreads();
    }
    int run = part[t] - local;   // exclusive prefix
    for (int i = beg; i < end; ++i) {
        row_start[i] = run; cursor[i] = run;
        run += cnt[i];
    }
    if (t == 1023) row_start[N] = run;   // == E
}

__global__ void scatter_kernel(const int* __restrict__ src, const int* __restrict__ dst,
                               int* __restrict__ cursor, int* __restrict__ src_sorted, int E) {
    int e = blockIdx.x * 256 + threadIdx.x;
    if (e < E) {
        int p = atomicAdd(&cursor[dst[e]], 1);
        src_sorted[p] = src[e];
    }
}

// ---------------- input GEMM: h0 = g_feats @ W_in + b_in   [N,128]x[128,64] ----------------
__global__ __launch_bounds__(256) void in_gemm(const float* __restrict__ g,
                                               const float* __restrict__ W,
                                               const float* __restrict__ b,
                                               float* __restrict__ h0, int N) {
    __shared__ float gt[128][36];   // gt[k][r]
    int t = threadIdx.x;
    int n0 = blockIdx.x * 32;
#pragma unroll
    for (int i = 0; i < 4; ++i) {
        int ch = t + i * 256;           // 1024 float4 chunks: 32 rows x 32 chunks
        int r = ch >> 5, k0 = (ch & 31) << 2;
        float4 v = (n0 + r < N) ? *(const float4*)(g + (size_t)(n0 + r) * 128 + k0)
                                : make_float4(0.f, 0.f, 0.f, 0.f);
        gt[k0 + 0][r] = v.x; gt[k0 + 1][r] = v.y; gt[k0 + 2][r] = v.z; gt[k0 + 3][r] = v.w;
    }
    __syncthreads();
    int c = t & 63, rg = t >> 6;
    float acc[8];
#pragma unroll
    for (int j = 0; j < 8; ++j) acc[j] = 0.f;
#pragma unroll 4
    for (int k = 0; k < 128; ++k) {
        float w = W[k * 64 + c];
        const float* hp = &gt[k][rg * 8];
        float4 ha = *(const float4*)hp;
        float4 hb = *(const float4*)(hp + 4);
        acc[0] = fmaf(ha.x, w, acc[0]);
        acc[1] = fmaf(ha.y, w, acc[1]);
        acc[2] = fmaf(ha.z, w, acc[2]);
        acc[3] = fmaf(ha.w, w, acc[3]);
        acc[4] = fmaf(hb.x, w, acc[4]);
        acc[5] = fmaf(hb.y, w, acc[5]);
        acc[6] = fmaf(hb.z, w, acc[6]);
        acc[7] = fmaf(hb.w, w, acc[7]);
    }
    float bb = b[c];
#pragma unroll
    for (int j = 0; j < 8; ++j) {
        int r = rg * 8 + j;
        if (n0 + r < N) h0[(size_t)(n0 + r) * 64 + c] = acc[j] + bb;
    }
}

// ---------------- feat GEMM (MFMA bf16) + el/er epilogue -> fp8 feat ----------------
__global__ __launch_bounds__(512) void feat_gemm(const float* __restrict__ hin,
                                                 const unsigned short* __restrict__ Wswz,
                                                 const float* __restrict__ al,
                                                 const float* __restrict__ ar,
                                                 unsigned char* __restrict__ feat8,
                                                 __hip_bfloat16* __restrict__ el,
                                                 __hip_bfloat16* __restrict__ er, int N) {
    __shared__ unsigned short shA[32][72];        // bf16, padded
    __shared__ unsigned char sfp8[32][512];       // fp8 output staging
    int t = threadIdx.x;
    int n0 = blockIdx.x * 32;
    {
        int r = t >> 4, c0 = (t & 15) << 2;
        float4 v = (n0 + r < N) ? *(const float4*)(hin + (size_t)(n0 + r) * 64 + c0)
                                : make_float4(0.f, 0.f, 0.f, 0.f);
        *(ushort4*)&shA[r][c0] = make_ushort4(f2bfu(v.x), f2bfu(v.y), f2bfu(v.z), f2bfu(v.w));
    }
    __syncthreads();

    int lane = t & 63;
    int w = t >> 6;              // wave id == head
    int lr = lane & 15;
    int lg = lane >> 4;          // 0..3

    bf16x8 afrag[2][2];
#pragma unroll
    for (int rt = 0; rt < 2; ++rt)
#pragma unroll
        for (int ks = 0; ks < 2; ++ks)
            afrag[rt][ks] = *(const bf16x8*)&shA[rt * 16 + lr][ks * 32 + lg * 8];

    bf16x8 bfrag[4][2];
#pragma unroll
    for (int ct = 0; ct < 4; ++ct)
#pragma unroll
        for (int ks = 0; ks < 2; ++ks) {
            int fid = ((w * 4 + ct) * 2 + ks) * 64 + lane;
            bfrag[ct][ks] = *(const bf16x8*)(Wswz + (size_t)fid * 8);
        }

    f32x4 acc[2][4];
#pragma unroll
    for (int rt = 0; rt < 2; ++rt)
#pragma unroll
        for (int ct = 0; ct < 4; ++ct)
            acc[rt][ct] = (f32x4){0.f, 0.f, 0.f, 0.f};

#pragma unroll
    for (int rt = 0; rt < 2; ++rt)
#pragma unroll
        for (int ct = 0; ct < 4; ++ct) {
            acc[rt][ct] = __builtin_amdgcn_mfma_f32_16x16x32_bf16(afrag[rt][0], bfrag[ct][0], acc[rt][ct], 0, 0, 0);
            acc[rt][ct] = __builtin_amdgcn_mfma_f32_16x16x32_bf16(afrag[rt][1], bfrag[ct][1], acc[rt][ct], 0, 0, 0);
        }

    // ---- epilogue 1: fp8 into LDS (transpose for coalesced global store)
#pragma unroll
    for (int rt = 0; rt < 2; ++rt)
#pragma unroll
        for (int ct = 0; ct < 4; ++ct) {
            int col = w * 64 + ct * 16 + lr;
#pragma unroll
            for (int j = 0; j < 4; ++j)
                sfp8[rt * 16 + lg * 4 + j][col] = f2fp8(acc[rt][ct][j]);
        }

    // ---- epilogue 2: el/er partials (register-only)
    float alv[4], arv[4];
#pragma unroll
    for (int ct = 0; ct < 4; ++ct) {
        alv[ct] = al[w * 64 + ct * 16 + lr];
        arv[ct] = ar[w * 64 + ct * 16 + lr];
    }
    float elp[2][4], erp[2][4];
#pragma unroll
    for (int rt = 0; rt < 2; ++rt)
#pragma unroll
        for (int j = 0; j < 4; ++j) {
            float sl = 0.f, sr = 0.f;
#pragma unroll
            for (int ct = 0; ct < 4; ++ct) {
                sl = fmaf(acc[rt][ct][j], alv[ct], sl);
                sr = fmaf(acc[rt][ct][j], arv[ct], sr);
            }
            elp[rt][j] = sl; erp[rt][j] = sr;
        }
#pragma unroll
    for (int off = 1; off < 16; off <<= 1)
#pragma unroll
        for (int rt = 0; rt < 2; ++rt)
#pragma unroll
            for (int j = 0; j < 4; ++j) {
                elp[rt][j] += __shfl_xor(elp[rt][j], off, 64);
                erp[rt][j] += __shfl_xor(erp[rt][j], off, 64);
            }
    if (lr == 0) {
#pragma unroll
        for (int rt = 0; rt < 2; ++rt)
#pragma unroll
            for (int j = 0; j < 4; ++j) {
                int r = rt * 16 + lg * 4 + j;
                if (n0 + r < N) {
                    el[(size_t)(n0 + r) * 8 + w] = __float2bfloat16(elp[rt][j]);
                    er[(size_t)(n0 + r) * 8 + w] = __float2bfloat16(erp[rt][j]);
                }
            }
    }

    // ---- coalesced fp8 store
    __syncthreads();
    {
        const uint4* src = (const uint4*)&sfp8[0][0];
        uint4* dst = (uint4*)(feat8 + (size_t)n0 * 512);
        int i0 = t * 2;
        if ((size_t)n0 * 512 + (size_t)(i0 + 2) * 16 <= (size_t)N * 512) {
            dst[i0] = src[i0];
            dst[i0 + 1] = src[i0 + 1];
        }
    }
}

// ---------------- GAT aggregation: one wave per dst node, single pass, fp8 feat ----------
// Per 8-edge sub-chunk, lane (h*8+e) computes THE exp for (edge e, head h);
// gather loop shfl-broadcasts alpha & src, 8 independent 8B loads in flight.
// __launch_bounds__(256, 8) pins regalloc under the 64-VGPR occupancy step (R6 lesson).
template <bool RELU>
__global__ __launch_bounds__(256, 8) void gat_aggregate(
    const unsigned char* __restrict__ feat8, const __hip_bfloat16* __restrict__ el,
    const __hip_bfloat16* __restrict__ er, const float* __restrict__ bias,
    const int* __restrict__ row_start, const int* __restrict__ src_sorted,
    float* __restrict__ hout, int N) {
    int lane = threadIdx.x & 63;
    int n = blockIdx.x * 4 + (threadIdx.x >> 6);
    if (n >= N) return;
    int h = lane >> 3;
    float erh = bf2f(er[(size_t)n * 8 + h]);
    int row = row_start[n];
    int deg = row_start[n + 1] - row;
    const unsigned char* featl = feat8 + lane * 8;  // per-lane base

    float acc[8];
#pragma unroll
    for (int j = 0; j < 8; ++j) acc[j] = 0.f;
    float den = 0.f;

    for (int base = 0; base < deg; base += 64) {
        int cnt = min(deg - base, 64);
        int sv = (lane < cnt) ? src_sorted[row + base + lane] : 0;
        int nsub = cnt & ~7;
        for (int i0 = 0; i0 < nsub; i0 += 8) {
            // exp-dedup: this lane owns (edge = i0 + (lane&7), head = lane>>3)
            int se = __shfl(sv, i0 + (lane & 7), 64);
            float ve = bf2f(el[(size_t)se * 8 + h]) + erh;
            ve = fmaxf(ve, NEG_SLOPE * ve);
            float am = __expf(ve);
            int hb = lane & 0x38;
#pragma unroll
            for (int e = 0; e < 8; ++e) {
                float a = __shfl(am, hb | e, 64);
                int s = __shfl(sv, i0 + e, 64);
                uint2 u = *(const uint2*)(featl + (size_t)s * 512);
                den += a;
                float f[8];
                unpack8_fp8(u, f);
#pragma unroll
                for (int j = 0; j < 8; ++j) acc[j] = fmaf(a, f[j], acc[j]);
            }
        }
        for (int i = nsub; i < cnt; ++i) {
            int s = __shfl(sv, i, 64);
            uint2 u = *(const uint2*)(featl + (size_t)s * 512);
            float v = bf2f(el[(size_t)s * 8 + h]) + erh;
            v = fmaxf(v, NEG_SLOPE * v);
            float a = __expf(v);
            den += a;
            float f[8];
            unpack8_fp8(u, f);
#pragma unroll
            for (int j = 0; j < 8; ++j) acc[j] = fmaf(a, f[j], acc[j]);
        }
    }

    float invd = deg > 0 ? 1.f / den : 0.f;
    const float4* bp = (const float4*)(bias + lane * 8);
    float4 b0 = bp[0], b1 = bp[1];
    float o[8];
    o[0] = fmaf(acc[0], invd, b0.x); o[1] = fmaf(acc[1], invd, b0.y);
    o[2] = fmaf(acc[2], invd, b0.z); o[3] = fmaf(acc[3], invd, b0.w);
    o[4] = fmaf(acc[4], invd, b1.x); o[5] = fmaf(acc[5], invd, b1.y);
    o[6] = fmaf(acc[6], invd, b1.z); o[7] = fmaf(acc[7], invd, b1.w);

    // head-mean: sum across lanes differing in head bits (3,4,5)
#pragma unroll
    for (int off = 8; off < 64; off <<= 1)
#pragma unroll
        for (int j = 0; j < 8; ++j)
            o[j] += __shfl_xor(o[j], off, 64);

    if (lane < 8) {
#pragma unroll
        for (int j = 0; j < 8; ++j) {
            o[j] *= 0.125f;
            if (RELU) o[j] = fmaxf(o[j], 0.f);
        }
        float4* op = (float4*)(hout + (size_t)n * 64 + lane * 8);
        op[0] = make_float4(o[0], o[1], o[2], o[3]);
        op[1] = make_float4(o[4], o[5], o[6], o[7]);
    }
}

// ---------------- per-graph readout partial sums (nodes sorted by graph id) ----------------
__global__ __launch_bounds__(256) void readout_partial(const float* __restrict__ h2,
                                                       const int* __restrict__ gid,
                                                       float* __restrict__ hg, int N) {
    int c = threadIdx.x & 63;
    int r = threadIdx.x >> 6;
    int n0 = blockIdx.x * 256;
    float sum = 0.f; int cur = -1;
    int nend = n0 + 256; if (nend > N) nend = N;
    for (int n = n0 + r; n < nend; n += 4) {
        int g = gid[n];
        if (g != cur) {
            if (cur >= 0) atomicAdd(&hg[cur * 64 + c], sum);
            cur = g; sum = 0.f;
        }
        sum += h2[(size_t)n * 64 + c];
    }
    if (cur >= 0) atomicAdd(&hg[cur * 64 + c], sum);
}

// ---------------- final head: counts, mean, GEMM 16x64x10, softmax ----------------
__global__ __launch_bounds__(256) void head_kernel(const float* __restrict__ hg_sum,
                                                   const int* __restrict__ gid,
                                                   const float* __restrict__ W_head,
                                                   const float* __restrict__ b_head,
                                                   float* __restrict__ out, int N) {
    __shared__ int scnt[16];
    __shared__ float shg[16 * 64];
    __shared__ float slog[16 * 10];
    int t = threadIdx.x;
    if (t < 16) scnt[t] = 0;
    __syncthreads();
    for (int n = t; n < N; n += 256) atomicAdd(&scnt[gid[n]], 1);
    __syncthreads();
    for (int i = t; i < 1024; i += 256) {
        int g = i >> 6;
        shg[i] = hg_sum[i] / fmaxf((float)scnt[g], 1.f);
    }
    __syncthreads();
    if (t < 160) {
        int g = t / 10, c = t % 10;
        float acc = b_head[c];
#pragma unroll 16
        for (int k = 0; k < 64; ++k) acc = fmaf(shg[g * 64 + k], W_head[k * 10 + c], acc);
        slog[g * 10 + c] = acc;
    }
    __syncthreads();
    if (t < 16) {
        float mx = -INFINITY;
#pragma unroll
        for (int c = 0; c < 10; ++c) mx = fmaxf(mx, slog[t * 10 + c]);
        float e[10], s = 0.f;
#pragma unroll
        for (int c = 0; c < 10; ++c) { e[c] = __expf(slog[t * 10 + c] - mx); s += e[c]; }
        float inv = 1.f / s;
#pragma unroll
        for (int c = 0; c < 10; ++c) out[t * 10 + c] = e[c] * inv;
    }
}

extern "C" void kernel_launch(void* const* d_in, const int* in_sizes, int n_in,
                              void* d_out, int out_size, void* d_ws, size_t ws_size,
                              hipStream_t stream) {
    const float* g_feats  = (const float*)d_in[0];
    const int*   edge_src = (const int*)d_in[1];
    const int*   edge_dst = (const int*)d_in[2];
    const int*   gids     = (const int*)d_in[3];
    const float* W_in     = (const float*)d_in[4];
    const float* b_in     = (const float*)d_in[5];
    const float* W1       = (const float*)d_in[6];
    const float* attn_l1  = (const float*)d_in[7];
    const float* attn_r1  = (const float*)d_in[8];
    const float* bias1    = (const float*)d_in[9];
    const float* W2       = (const float*)d_in[10];
    const float* attn_l2  = (const float*)d_in[11];
    const float* attn_r2  = (const float*)d_in[12];
    const float* bias2    = (const float*)d_in[13];
    const float* W_head   = (const float*)d_in[14];
    const float* b_head   = (const float*)d_in[15];
    float* out = (float*)d_out;

    const int N = in_sizes[3];
    const int E = in_sizes[1];

    // workspace layout (16B-aligned sections)
    unsigned char* feat8 = (unsigned char*)d_ws;            // N*512 bytes (fp8)
    float* h0 = (float*)(feat8 + (size_t)N * 512);          // N*64 f32
    float* h1 = h0 + (size_t)N * 64;                        // N*64
    float* h2 = h1 + (size_t)N * 64;                        // N*64
    float* hg = h2 + (size_t)N * 64;                        // 16*64
    __hip_bfloat16* el = (__hip_bfloat16*)(hg + 16 * 64);   // N*8 bf16
    __hip_bfloat16* er = el + (size_t)N * 8;                // N*8 bf16
    unsigned short* Wz1 = (unsigned short*)(er + (size_t)N * 8);  // 32768 bf16
    unsigned short* Wz2 = Wz1 + 32768;                      // 32768 bf16
    int* cnt        = (int*)(Wz2 + 32768);                  // N
    int* row_start  = cnt + N;                              // N+1
    int* cursor     = row_start + N + 1;                    // N
    int* src_sorted = cursor + N;                           // E

    int eb = (E + 255) / 256;
    int nb4 = (N + 3) / 4;
    int nb32 = (N + 31) / 32;
    int nb256 = (N + 255) / 256;

    prep_all<<<36, 256, 0, stream>>>(W1, W2, Wz1, Wz2, cnt, hg, N);
    hist_kernel<<<eb, 256, 0, stream>>>(edge_dst, cnt, E);
    scan_kernel<<<1, 1024, 0, stream>>>(cnt, row_start, cursor, N);
    scatter_kernel<<<eb, 256, 0, stream>>>(edge_src, edge_dst, cursor, src_sorted, E);

    in_gemm<<<nb32, 256, 0, stream>>>(g_feats, W_in, b_in, h0, N);

    feat_gemm<<<nb32, 512, 0, stream>>>(h0, Wz1, attn_l1, attn_r1, feat8, el, er, N);
    gat_aggregate<true><<<nb4, 256, 0, stream>>>(feat8, el, er, bias1, row_start, src_sorted, h1, N);

    feat_gemm<<<nb32, 512, 0, stream>>>(h1, Wz2, attn_l2, attn_r2, feat8, el, er, N);
    gat_aggregate<false><<<nb4, 256, 0, stream>>>(feat8, el, er, bias2, row_start, src_sorted, h2, N);

    readout_partial<<<nb256, 256, 0, stream>>>(h2, gids, hg, N);
    head_kernel<<<1, 256, 0, stream>>>(hg, gids, W_head, b_head, out, N);
}

// Round 13
// 265.473 us; speedup vs baseline: 1.2366x; 1.0879x over previous
//
#include <hip/hip_runtime.h>
#include <hip/hip_bf16.h>
#include <math.h>

// Problem constants (fixed by the reference):
// N=20000, E=320000, DIN=128, DH=64, H=8, B=16, C=10, NEG_SLOPE=0.2

#define NEG_SLOPE 0.2f

typedef float f32x2 __attribute__((ext_vector_type(2)));
typedef float f32x4 __attribute__((ext_vector_type(4)));
typedef short bf16x8 __attribute__((ext_vector_type(8)));

__device__ __forceinline__ float bf2f(__hip_bfloat16 b) { return __bfloat162float(b); }
__device__ __forceinline__ unsigned short f2bfu(float x) {
    __hip_bfloat16 b = __float2bfloat16(x);
    return *(unsigned short*)&b;
}

// fp8 e4m3 pack/unpack (OCP on gfx950)
__device__ __forceinline__ unsigned char f2fp8(float x) {
    unsigned int u = __builtin_amdgcn_cvt_pk_fp8_f32(x, x, 0, false);
    return (unsigned char)(u & 0xff);
}
__device__ __forceinline__ void unpack8_fp8(uint2 u, float* f) {
    f32x2 a = __builtin_amdgcn_cvt_pk_f32_fp8(u.x, false);
    f32x2 b = __builtin_amdgcn_cvt_pk_f32_fp8(u.x, true);
    f32x2 c = __builtin_amdgcn_cvt_pk_f32_fp8(u.y, false);
    f32x2 d = __builtin_amdgcn_cvt_pk_f32_fp8(u.y, true);
    f[0] = a[0]; f[1] = a[1]; f[2] = b[0]; f[3] = b[1];
    f[4] = c[0]; f[5] = c[1]; f[6] = d[0]; f[7] = d[1];
}

// ---------------- prep_all: W-swizzle both layers + zero cnt & hg ------
// blocks 0..15: W1 swizzle; 16..31: W2 swizzle; 32..35: zero cnt; block 32 also zeroes hg.
__global__ __launch_bounds__(256) void prep_all(const float* __restrict__ W1,
                                                const float* __restrict__ W2,
                                                unsigned short* __restrict__ Bz1,
                                                unsigned short* __restrict__ Bz2,
                                                int* __restrict__ cnt,
                                                float* __restrict__ hg, int N) {
    int b = blockIdx.x;
    if (b < 32) {
        const float* W = (b < 16) ? W1 : W2;
        unsigned short* Wswz = (b < 16) ? Bz1 : Bz2;
        int fid = (b & 15) * 256 + threadIdx.x;     // 0..4095
        int lane = fid & 63;
        int ks = (fid >> 6) & 1;
        int ctg = fid >> 7;                          // 0..31
        int col = ctg * 16 + (lane & 15);
        int k0 = ks * 32 + ((lane >> 4) << 3);
        unsigned short v[8];
#pragma unroll
        for (int j = 0; j < 8; ++j) v[j] = f2bfu(W[(k0 + j) * 512 + col]);
        ushort4* dst = (ushort4*)(Wswz + (size_t)fid * 8);
        dst[0] = make_ushort4(v[0], v[1], v[2], v[3]);
        dst[1] = make_ushort4(v[4], v[5], v[6], v[7]);
    } else {
        for (int i = (b - 32) * 256 + threadIdx.x; i < N; i += 4 * 256) cnt[i] = 0;
        if (b == 32) {
            for (int i = threadIdx.x; i < 16 * 64; i += 256) hg[i] = 0.f;
        }
    }
}

// ---------------- scan (exclusive prefix over cnt) ----------------
__global__ __launch_bounds__(1024) void scan_kernel(const int* __restrict__ cnt,
                                                    int* __restrict__ row_start,
                                                    int* __restrict__ cursor, int N) {
    __shared__ int part[1024];
    int t = threadIdx.x;
    int CH = (N + 1023) >> 10;
    int beg = t * CH;
    int end = beg + CH; if (end > N) end = N;
    if (beg > N) beg = N;
    int local = 0;
    for (int i = beg; i < end; ++i) local += cnt[i];
    part[t] = local;
    __syncthreads();
    for (int off = 1; off < 1024; off <<= 1) {
        int v = (t >= off) ? part[t - off] : 0;
        __syncthreads();
        part[t] += v;
        __syncthreads();
    }
    int run = part[t] - local;   // exclusive prefix
    for (int i = beg; i < end; ++i) {
        row_start[i] = run; cursor[i] = run;
        run += cnt[i];
    }
    if (t == 1023) row_start[N] = run;   // == E
}

// ---------------- FUSED: input GEMM + edge histogram (independent work, one dispatch) ------
// blocks [0, nbGemm): h0 = g @ W_in + b_in ; blocks [nbGemm, ...): hist atomics.
__global__ __launch_bounds__(256) void in_gemm_hist(const float* __restrict__ g,
                                                    const float* __restrict__ W,
                                                    const float* __restrict__ b,
                                                    float* __restrict__ h0,
                                                    const int* __restrict__ edge_dst,
                                                    int* __restrict__ cnt,
                                                    int N, int E, int nbGemm) {
    __shared__ float gt[128][36];   // gt[k][r]
    int t = threadIdx.x;
    if (blockIdx.x >= nbGemm) {
        int e = (blockIdx.x - nbGemm) * 256 + t;
        if (e < E) atomicAdd(&cnt[edge_dst[e]], 1);
        return;
    }
    int n0 = blockIdx.x * 32;
#pragma unroll
    for (int i = 0; i < 4; ++i) {
        int ch = t + i * 256;           // 1024 float4 chunks: 32 rows x 32 chunks
        int r = ch >> 5, k0 = (ch & 31) << 2;
        float4 v = (n0 + r < N) ? *(const float4*)(g + (size_t)(n0 + r) * 128 + k0)
                                : make_float4(0.f, 0.f, 0.f, 0.f);
        gt[k0 + 0][r] = v.x; gt[k0 + 1][r] = v.y; gt[k0 + 2][r] = v.z; gt[k0 + 3][r] = v.w;
    }
    __syncthreads();
    int c = t & 63, rg = t >> 6;
    float acc[8];
#pragma unroll
    for (int j = 0; j < 8; ++j) acc[j] = 0.f;
#pragma unroll 4
    for (int k = 0; k < 128; ++k) {
        float w = W[k * 64 + c];
        const float* hp = &gt[k][rg * 8];
        float4 ha = *(const float4*)hp;
        float4 hb = *(const float4*)(hp + 4);
        acc[0] = fmaf(ha.x, w, acc[0]);
        acc[1] = fmaf(ha.y, w, acc[1]);
        acc[2] = fmaf(ha.z, w, acc[2]);
        acc[3] = fmaf(ha.w, w, acc[3]);
        acc[4] = fmaf(hb.x, w, acc[4]);
        acc[5] = fmaf(hb.y, w, acc[5]);
        acc[6] = fmaf(hb.z, w, acc[6]);
        acc[7] = fmaf(hb.w, w, acc[7]);
    }
    float bb = b[c];
#pragma unroll
    for (int j = 0; j < 8; ++j) {
        int r = rg * 8 + j;
        if (n0 + r < N) h0[(size_t)(n0 + r) * 64 + c] = acc[j] + bb;
    }
}

// ---------------- feat GEMM (MFMA bf16) + el/er epilogue -> fp8 feat ----------------
// template<FUSE_SCATTER>: blocks >= nbGemm run the CSR scatter (independent of GEMM inputs).
template <bool FUSE_SCATTER>
__global__ __launch_bounds__(512) void feat_gemm(const float* __restrict__ hin,
                                                 const unsigned short* __restrict__ Wswz,
                                                 const float* __restrict__ al,
                                                 const float* __restrict__ ar,
                                                 unsigned char* __restrict__ feat8,
                                                 __hip_bfloat16* __restrict__ el,
                                                 __hip_bfloat16* __restrict__ er,
                                                 const int* __restrict__ edge_src,
                                                 const int* __restrict__ edge_dst,
                                                 int* __restrict__ cursor,
                                                 int* __restrict__ src_sorted,
                                                 int N, int E, int nbGemm) {
    __shared__ unsigned short shA[32][72];        // bf16, padded
    __shared__ unsigned char sfp8[32][512];       // fp8 output staging
    int t = threadIdx.x;
    if (FUSE_SCATTER && blockIdx.x >= nbGemm) {
        int e = (blockIdx.x - nbGemm) * 512 + t;
        if (e < E) {
            int p = atomicAdd(&cursor[edge_dst[e]], 1);
            src_sorted[p] = edge_src[e];
        }
        return;
    }
    int n0 = blockIdx.x * 32;
    {
        int r = t >> 4, c0 = (t & 15) << 2;
        float4 v = (n0 + r < N) ? *(const float4*)(hin + (size_t)(n0 + r) * 64 + c0)
                                : make_float4(0.f, 0.f, 0.f, 0.f);
        *(ushort4*)&shA[r][c0] = make_ushort4(f2bfu(v.x), f2bfu(v.y), f2bfu(v.z), f2bfu(v.w));
    }
    __syncthreads();

    int lane = t & 63;
    int w = t >> 6;              // wave id == head
    int lr = lane & 15;
    int lg = lane >> 4;          // 0..3

    bf16x8 afrag[2][2];
#pragma unroll
    for (int rt = 0; rt < 2; ++rt)
#pragma unroll
        for (int ks = 0; ks < 2; ++ks)
            afrag[rt][ks] = *(const bf16x8*)&shA[rt * 16 + lr][ks * 32 + lg * 8];

    bf16x8 bfrag[4][2];
#pragma unroll
    for (int ct = 0; ct < 4; ++ct)
#pragma unroll
        for (int ks = 0; ks < 2; ++ks) {
            int fid = ((w * 4 + ct) * 2 + ks) * 64 + lane;
            bfrag[ct][ks] = *(const bf16x8*)(Wswz + (size_t)fid * 8);
        }

    f32x4 acc[2][4];
#pragma unroll
    for (int rt = 0; rt < 2; ++rt)
#pragma unroll
        for (int ct = 0; ct < 4; ++ct)
            acc[rt][ct] = (f32x4){0.f, 0.f, 0.f, 0.f};

#pragma unroll
    for (int rt = 0; rt < 2; ++rt)
#pragma unroll
        for (int ct = 0; ct < 4; ++ct) {
            acc[rt][ct] = __builtin_amdgcn_mfma_f32_16x16x32_bf16(afrag[rt][0], bfrag[ct][0], acc[rt][ct], 0, 0, 0);
            acc[rt][ct] = __builtin_amdgcn_mfma_f32_16x16x32_bf16(afrag[rt][1], bfrag[ct][1], acc[rt][ct], 0, 0, 0);
        }

    // ---- epilogue 1: fp8 into LDS (transpose for coalesced global store)
#pragma unroll
    for (int rt = 0; rt < 2; ++rt)
#pragma unroll
        for (int ct = 0; ct < 4; ++ct) {
            int col = w * 64 + ct * 16 + lr;
#pragma unroll
            for (int j = 0; j < 4; ++j)
                sfp8[rt * 16 + lg * 4 + j][col] = f2fp8(acc[rt][ct][j]);
        }

    // ---- epilogue 2: el/er partials (register-only)
    float alv[4], arv[4];
#pragma unroll
    for (int ct = 0; ct < 4; ++ct) {
        alv[ct] = al[w * 64 + ct * 16 + lr];
        arv[ct] = ar[w * 64 + ct * 16 + lr];
    }
    float elp[2][4], erp[2][4];
#pragma unroll
    for (int rt = 0; rt < 2; ++rt)
#pragma unroll
        for (int j = 0; j < 4; ++j) {
            float sl = 0.f, sr = 0.f;
#pragma unroll
            for (int ct = 0; ct < 4; ++ct) {
                sl = fmaf(acc[rt][ct][j], alv[ct], sl);
                sr = fmaf(acc[rt][ct][j], arv[ct], sr);
            }
            elp[rt][j] = sl; erp[rt][j] = sr;
        }
#pragma unroll
    for (int off = 1; off < 16; off <<= 1)
#pragma unroll
        for (int rt = 0; rt < 2; ++rt)
#pragma unroll
            for (int j = 0; j < 4; ++j) {
                elp[rt][j] += __shfl_xor(elp[rt][j], off, 64);
                erp[rt][j] += __shfl_xor(erp[rt][j], off, 64);
            }
    if (lr == 0) {
#pragma unroll
        for (int rt = 0; rt < 2; ++rt)
#pragma unroll
            for (int j = 0; j < 4; ++j) {
                int r = rt * 16 + lg * 4 + j;
                if (n0 + r < N) {
                    el[(size_t)(n0 + r) * 8 + w] = __float2bfloat16(elp[rt][j]);
                    er[(size_t)(n0 + r) * 8 + w] = __float2bfloat16(erp[rt][j]);
                }
            }
    }

    // ---- coalesced fp8 store
    __syncthreads();
    {
        const uint4* src = (const uint4*)&sfp8[0][0];
        uint4* dst = (uint4*)(feat8 + (size_t)n0 * 512);
        int i0 = t * 2;
        if ((size_t)n0 * 512 + (size_t)(i0 + 2) * 16 <= (size_t)N * 512) {
            dst[i0] = src[i0];
            dst[i0 + 1] = src[i0 + 1];
        }
    }
}

// ---------------- GAT aggregation: one wave per dst node, single pass, fp8 feat ----------
template <bool RELU>
__global__ __launch_bounds__(256, 8) void gat_aggregate(
    const unsigned char* __restrict__ feat8, const __hip_bfloat16* __restrict__ el,
    const __hip_bfloat16* __restrict__ er, const float* __restrict__ bias,
    const int* __restrict__ row_start, const int* __restrict__ src_sorted,
    float* __restrict__ hout, int N) {
    int lane = threadIdx.x & 63;
    int n = blockIdx.x * 4 + (threadIdx.x >> 6);
    if (n >= N) return;
    int h = lane >> 3;
    float erh = bf2f(er[(size_t)n * 8 + h]);
    int row = row_start[n];
    int deg = row_start[n + 1] - row;
    const unsigned char* featl = feat8 + lane * 8;  // per-lane base

    float acc[8];
#pragma unroll
    for (int j = 0; j < 8; ++j) acc[j] = 0.f;
    float den = 0.f;

    for (int base = 0; base < deg; base += 64) {
        int cnt = min(deg - base, 64);
        int sv = (lane < cnt) ? src_sorted[row + base + lane] : 0;
        int nsub = cnt & ~7;
        for (int i0 = 0; i0 < nsub; i0 += 8) {
            // exp-dedup: this lane owns (edge = i0 + (lane&7), head = lane>>3)
            int se = __shfl(sv, i0 + (lane & 7), 64);
            float ve = bf2f(el[(size_t)se * 8 + h]) + erh;
            ve = fmaxf(ve, NEG_SLOPE * ve);
            float am = __expf(ve);
            int hb = lane & 0x38;
#pragma unroll
            for (int e = 0; e < 8; ++e) {
                float a = __shfl(am, hb | e, 64);
                int s = __shfl(sv, i0 + e, 64);
                uint2 u = *(const uint2*)(featl + (size_t)s * 512);
                den += a;
                float f[8];
                unpack8_fp8(u, f);
#pragma unroll
                for (int j = 0; j < 8; ++j) acc[j] = fmaf(a, f[j], acc[j]);
            }
        }
        for (int i = nsub; i < cnt; ++i) {
            int s = __shfl(sv, i, 64);
            uint2 u = *(const uint2*)(featl + (size_t)s * 512);
            float v = bf2f(el[(size_t)s * 8 + h]) + erh;
            v = fmaxf(v, NEG_SLOPE * v);
            float a = __expf(v);
            den += a;
            float f[8];
            unpack8_fp8(u, f);
#pragma unroll
            for (int j = 0; j < 8; ++j) acc[j] = fmaf(a, f[j], acc[j]);
        }
    }

    float invd = deg > 0 ? 1.f / den : 0.f;
    const float4* bp = (const float4*)(bias + lane * 8);
    float4 b0 = bp[0], b1 = bp[1];
    float o[8];
    o[0] = fmaf(acc[0], invd, b0.x); o[1] = fmaf(acc[1], invd, b0.y);
    o[2] = fmaf(acc[2], invd, b0.z); o[3] = fmaf(acc[3], invd, b0.w);
    o[4] = fmaf(acc[4], invd, b1.x); o[5] = fmaf(acc[5], invd, b1.y);
    o[6] = fmaf(acc[6], invd, b1.z); o[7] = fmaf(acc[7], invd, b1.w);

    // head-mean: sum across lanes differing in head bits (3,4,5)
#pragma unroll
    for (int off = 8; off < 64; off <<= 1)
#pragma unroll
        for (int j = 0; j < 8; ++j)
            o[j] += __shfl_xor(o[j], off, 64);

    if (lane < 8) {
#pragma unroll
        for (int j = 0; j < 8; ++j) {
            o[j] *= 0.125f;
            if (RELU) o[j] = fmaxf(o[j], 0.f);
        }
        float4* op = (float4*)(hout + (size_t)n * 64 + lane * 8);
        op[0] = make_float4(o[0], o[1], o[2], o[3]);
        op[1] = make_float4(o[4], o[5], o[6], o[7]);
    }
}

// ---------------- per-graph readout partial sums (nodes sorted by graph id) ----------------
__global__ __launch_bounds__(256) void readout_partial(const float* __restrict__ h2,
                                                       const int* __restrict__ gid,
                                                       float* __restrict__ hg, int N) {
    int c = threadIdx.x & 63;
    int r = threadIdx.x >> 6;
    int n0 = blockIdx.x * 256;
    float sum = 0.f; int cur = -1;
    int nend = n0 + 256; if (nend > N) nend = N;
    for (int n = n0 + r; n < nend; n += 4) {
        int g = gid[n];
        if (g != cur) {
            if (cur >= 0) atomicAdd(&hg[cur * 64 + c], sum);
            cur = g; sum = 0.f;
        }
        sum += h2[(size_t)n * 64 + c];
    }
    if (cur >= 0) atomicAdd(&hg[cur * 64 + c], sum);
}

// ---------------- final head: counts via binary search, mean, GEMM 16x64x10, softmax ------
__global__ __launch_bounds__(256) void head_kernel(const float* __restrict__ hg_sum,
                                                   const int* __restrict__ gid,
                                                   const float* __restrict__ W_head,
                                                   const float* __restrict__ b_head,
                                                   float* __restrict__ out, int N) {
    __shared__ int scnt[16];
    __shared__ float shg[16 * 64];
    __shared__ float slog[16 * 10];
    int t = threadIdx.x;
    if (t < 17) {
        // boundary[t] = first index with gid >= t (gids sorted)
        int lo = 0, hi = N;
        while (lo < hi) { int m = (lo + hi) >> 1; if (gid[m] < t) lo = m + 1; else hi = m; }
        if (t < 16) scnt[t] = lo;          // temporarily store lower bound
        else shg[0] = 0.f;                 // dummy to keep t==16 path harmless
        if (t == 16) slog[0] = (float)lo;  // stash upper sentinel (=N)
    }
    __syncthreads();
    if (t < 16) {
        int hi = (t == 15) ? (int)slog[0] : scnt[t + 1];
        scnt[t] = hi - scnt[t];
    }
    __syncthreads();
    for (int i = t; i < 1024; i += 256) {
        int g = i >> 6;
        shg[i] = hg_sum[i] / fmaxf((float)scnt[g], 1.f);
    }
    __syncthreads();
    if (t < 160) {
        int g = t / 10, c = t % 10;
        float acc = b_head[c];
#pragma unroll 16
        for (int k = 0; k < 64; ++k) acc = fmaf(shg[g * 64 + k], W_head[k * 10 + c], acc);
        slog[g * 10 + c] = acc;
    }
    __syncthreads();
    if (t < 16) {
        float mx = -INFINITY;
#pragma unroll
        for (int c = 0; c < 10; ++c) mx = fmaxf(mx, slog[t * 10 + c]);
        float e[10], s = 0.f;
#pragma unroll
        for (int c = 0; c < 10; ++c) { e[c] = __expf(slog[t * 10 + c] - mx); s += e[c]; }
        float inv = 1.f / s;
#pragma unroll
        for (int c = 0; c < 10; ++c) out[t * 10 + c] = e[c] * inv;
    }
}

extern "C" void kernel_launch(void* const* d_in, const int* in_sizes, int n_in,
                              void* d_out, int out_size, void* d_ws, size_t ws_size,
                              hipStream_t stream) {
    const float* g_feats  = (const float*)d_in[0];
    const int*   edge_src = (const int*)d_in[1];
    const int*   edge_dst = (const int*)d_in[2];
    const int*   gids     = (const int*)d_in[3];
    const float* W_in     = (const float*)d_in[4];
    const float* b_in     = (const float*)d_in[5];
    const float* W1       = (const float*)d_in[6];
    const float* attn_l1  = (const float*)d_in[7];
    const float* attn_r1  = (const float*)d_in[8];
    const float* bias1    = (const float*)d_in[9];
    const float* W2       = (const float*)d_in[10];
    const float* attn_l2  = (const float*)d_in[11];
    const float* attn_r2  = (const float*)d_in[12];
    const float* bias2    = (const float*)d_in[13];
    const float* W_head   = (const float*)d_in[14];
    const float* b_head   = (const float*)d_in[15];
    float* out = (float*)d_out;

    const int N = in_sizes[3];
    const int E = in_sizes[1];

    // workspace layout (16B-aligned sections)
    unsigned char* feat8 = (unsigned char*)d_ws;            // N*512 bytes (fp8)
    float* h0 = (float*)(feat8 + (size_t)N * 512);          // N*64 f32
    float* h1 = h0 + (size_t)N * 64;                        // N*64
    float* h2 = h1 + (size_t)N * 64;                        // N*64
    float* hg = h2 + (size_t)N * 64;                        // 16*64
    __hip_bfloat16* el = (__hip_bfloat16*)(hg + 16 * 64);   // N*8 bf16
    __hip_bfloat16* er = el + (size_t)N * 8;                // N*8 bf16
    unsigned short* Wz1 = (unsigned short*)(er + (size_t)N * 8);  // 32768 bf16
    unsigned short* Wz2 = Wz1 + 32768;                      // 32768 bf16
    int* cnt        = (int*)(Wz2 + 32768);                  // N
    int* row_start  = cnt + N;                              // N+1
    int* cursor     = row_start + N + 1;                    // N
    int* src_sorted = cursor + N;                           // E

    int nb4 = (N + 3) / 4;
    int nb32 = (N + 31) / 32;
    int nb256 = (N + 255) / 256;
    int eb256 = (E + 255) / 256;
    int eb512 = (E + 511) / 512;

    prep_all<<<36, 256, 0, stream>>>(W1, W2, Wz1, Wz2, cnt, hg, N);
    // fused: input GEMM + edge histogram (independent)
    in_gemm_hist<<<nb32 + eb256, 256, 0, stream>>>(g_feats, W_in, b_in, h0,
                                                   edge_dst, cnt, N, E, nb32);
    scan_kernel<<<1, 1024, 0, stream>>>(cnt, row_start, cursor, N);
    // fused: feat GEMM layer1 + CSR scatter (independent)
    feat_gemm<true><<<nb32 + eb512, 512, 0, stream>>>(h0, Wz1, attn_l1, attn_r1,
                                                      feat8, el, er,
                                                      edge_src, edge_dst, cursor, src_sorted,
                                                      N, E, nb32);
    gat_aggregate<true><<<nb4, 256, 0, stream>>>(feat8, el, er, bias1, row_start, src_sorted, h1, N);

    feat_gemm<false><<<nb32, 512, 0, stream>>>(h1, Wz2, attn_l2, attn_r2,
                                               feat8, el, er,
                                               nullptr, nullptr, nullptr, nullptr,
                                               N, E, nb32);
    gat_aggregate<false><<<nb4, 256, 0, stream>>>(feat8, el, er, bias2, row_start, src_sorted, h2, N);

    readout_partial<<<nb256, 256, 0, stream>>>(h2, gids, hg, N);
    head_kernel<<<1, 256, 0, stream>>>(hg, gids, W_head, b_head, out, N);
}